// Round 4
// baseline (665.150 us; speedup 1.0000x reference)
//
#include <hip/hip_runtime.h>
#include <hip/hip_bf16.h>
#include <stdint.h>
#include <stddef.h>

// z[8192,512] f32, mu[1000,8,512] f32 -> out = concat(logits[8192,1000], min_dist_sq[8192,1000]) f32
#define B_ROWS 8192
#define C_CLS  1000
#define NPROTO 8000
#define D_DIM  512

#define TK 32                 // K-tile (one MFMA-K)
#define NKT 16                // 512/32
#define MT 32                 // proto tiles (A side)
#define NT 32                 // z tiles (B side)

typedef __bf16 bf16x8 __attribute__((ext_vector_type(8)));
typedef float  f32x4  __attribute__((ext_vector_type(4)));

#define AS1 __attribute__((address_space(1)))
#define AS3 __attribute__((address_space(3)))

__device__ __forceinline__ void gload_lds16(const void* g, void* l) {
  __builtin_amdgcn_global_load_lds((const AS1 uint32_t*)g, (AS3 uint32_t*)l, 16, 0, 0);
}

__device__ __forceinline__ f32x4 mfma16(bf16x8 a, bf16x8 b, f32x4 c) {
  return __builtin_amdgcn_mfma_f32_16x16x32_bf16(a, b, c, 0, 0, 0);
}

// LDS map: buf d (d=0,1): A(mu) 16 KB at d*32768, B(z) 16 KB at d*32768+16384.
// 66 KB total -> 2 blocks/CU (the round-4 structural lever).
#define ABUF(d) ((d) * 32768)
#define BBUF(d) ((d) * 32768 + 16384)
#define Z2OFF   65536
#define MU2OFF  66560
#define LDS_BYTES 67584

// ---------- prep: fp32 -> bf16 cast + row sum-of-squares (unchanged from r3) ----------
__global__ void prep_rows(const float* __restrict__ z, const float* __restrict__ mu,
                          __bf16* __restrict__ zb, __bf16* __restrict__ mub,
                          float* __restrict__ z2, float* __restrict__ mu2) {
  const int r = blockIdx.x * 4 + (threadIdx.x >> 6);
  const int l = threadIdx.x & 63;
  const float* src; __bf16* dst; float* sq; int row;
  if (r < B_ROWS) { src = z;  dst = zb;  sq = z2;  row = r; }
  else            { src = mu; dst = mub; sq = mu2; row = r - B_ROWS; }
  const float4* s4 = (const float4*)(src + (size_t)row * D_DIM);
  float4 v0 = s4[l * 2], v1 = s4[l * 2 + 1];
  float ss = v0.x * v0.x + v0.y * v0.y + v0.z * v0.z + v0.w * v0.w
           + v1.x * v1.x + v1.y * v1.y + v1.z * v1.z + v1.w * v1.w;
  bf16x8 o;
  o[0] = (__bf16)v0.x; o[1] = (__bf16)v0.y; o[2] = (__bf16)v0.z; o[3] = (__bf16)v0.w;
  o[4] = (__bf16)v1.x; o[5] = (__bf16)v1.y; o[6] = (__bf16)v1.z; o[7] = (__bf16)v1.w;
  ((bf16x8*)(dst + (size_t)row * D_DIM))[l] = o;
  #pragma unroll
  for (int off = 32; off; off >>= 1) ss += __shfl_down(ss, off);
  if (l == 0) sq[row] = ss;
}

// ---------- fused GEMM(A=mu, B=z) + dist + min-over-P; BK=32, 2 blocks/CU ----------
__launch_bounds__(512, 4)
__global__ void proto_gemm(const __bf16* __restrict__ Zb, const __bf16* __restrict__ Mub,
                           const float* __restrict__ Z2, const float* __restrict__ Mu2,
                           float* __restrict__ logits, float* __restrict__ mind) {
  __shared__ __align__(16) unsigned char smem[LDS_BYTES];

  const int tid = threadIdx.x;
  const int l   = tid & 63;
  const int w   = tid >> 6;      // 8 waves: 2 (proto/M) x 4 (zrow/N)
  const int wm  = w >> 2;
  const int wn  = w & 3;

  // T1: XCD chunking (1024 blocks = 8 XCDs x 128)
  const int xcd = blockIdx.x & 7, cc = blockIdx.x >> 3;
  const int mt = (xcd & 1) * 16 + (cc >> 3);   // proto tile
  const int nt = (xcd >> 1) * 8 + (cc & 7);    // z tile

  // norms into LDS FIRST (their vmem loads retire before stages; keeps counted vmcnt clean)
  float* z2s  = (float*)(smem + Z2OFF);
  float* mu2s = (float*)(smem + MU2OFF);
  if (tid < 256) {
    z2s[tid] = Z2[nt * 256 + tid];
  } else {
    const int i = tid - 256;
    const int gp = mt * 256 + i;
    mu2s[i] = Mu2[gp < NPROTO ? gp : NPROTO - 1];
  }

  // ---- staging (both-sides chunk swizzle): tile row stride 64 B = 4 chunks of 16 B.
  // slot (r, kc) holds global k-chunk kc ^ rho(r), rho(r) = (r>>1)&3  (involution).
  // thread t stages slot (r = t>>2, kc = t&3) of rows [0,128) and [128,256).
  const int sr   = tid >> 2;
  const int scol = (((tid & 3) ^ ((tid >> 3) & 3)) * 8);   // rho same for r and r+128
  int p0 = mt * 256 + sr;        if (p0 > NPROTO - 1) p0 = NPROTO - 1;
  int p1 = mt * 256 + 128 + sr;  if (p1 > NPROTO - 1) p1 = NPROTO - 1;
  const __bf16* pA0 = Mub + (size_t)p0 * D_DIM + scol;
  const __bf16* pA1 = Mub + (size_t)p1 * D_DIM + scol;
  const __bf16* pB0 = Zb + (size_t)(nt * 256 + sr) * D_DIM + scol;
  const __bf16* pB1 = Zb + (size_t)(nt * 256 + 128 + sr) * D_DIM + scol;
  const int ldst = tid * 16;

  #define STAGE(T, D)                                              \
    {                                                              \
      gload_lds16(pA0 + (T) * TK, smem + ABUF(D) + ldst);          \
      gload_lds16(pA1 + (T) * TK, smem + ABUF(D) + 8192 + ldst);   \
      gload_lds16(pB0 + (T) * TK, smem + BBUF(D) + ldst);          \
      gload_lds16(pB1 + (T) * TK, smem + BBUF(D) + 8192 + ldst);   \
    }

  STAGE(0, 0);
  STAGE(1, 1);

  // reader offset: frag row = base + (l&15), logical k-chunk = l>>4; slot kc = (l>>4) ^ rho(row),
  // rho(row) = ((l&15)>>1)&3 = (l>>1)&3 (bases are multiples of 16).
  const int rofs = (l & 15) * 64 + ((((l >> 4) ^ ((l >> 1) & 3))) << 4);
  const int abase_w = wm * 8192;   // 128 proto-rows * 64 B
  const int bbase_w = wn * 4096;   // 64 z-rows * 64 B

  f32x4 acc[8][4];
  #pragma unroll
  for (int i = 0; i < 8; ++i)
    #pragma unroll
    for (int j = 0; j < 4; ++j) acc[i][j] = (f32x4){0.f, 0.f, 0.f, 0.f};

  // tile 0 landed: outstanding = z2/mu2(oldest) + stage0(4) + stage1(4); vmcnt(4) retires thru stage0
  asm volatile("s_waitcnt vmcnt(4)" ::: "memory");
  __builtin_amdgcn_s_barrier();

  // Per tile (r3-proven schedule at BK=32): all 12 reads early; mid barrier gates
  // re-stage of THIS buffer (2-deep prefetch); second MFMA half overlaps stage issue;
  // end: counted vmcnt + barrier. Never drains to 0 until the tail.
  #define KTILE(T, DOSTAGE, VMEND, DOEND)                                        \
  {                                                                              \
    constexpr int d_ = (T) & 1;                                                  \
    const unsigned char* ab = smem + ABUF(d_) + abase_w;                         \
    const unsigned char* bp = smem + BBUF(d_) + bbase_w;                         \
    bf16x8 bb[4], aa[8];                                                         \
    _Pragma("unroll")                                                            \
    for (int j = 0; j < 4; ++j) bb[j] = *(const bf16x8*)(bp + j * 1024 + rofs);  \
    _Pragma("unroll")                                                            \
    for (int i = 0; i < 4; ++i) aa[i] = *(const bf16x8*)(ab + i * 1024 + rofs);  \
    __builtin_amdgcn_s_setprio(1);                                               \
    _Pragma("unroll")                                                            \
    for (int i = 0; i < 4; ++i)                                                  \
      _Pragma("unroll")                                                          \
      for (int j = 0; j < 4; ++j)                                                \
        acc[i][j] = mfma16(aa[i], bb[j], acc[i][j]);                             \
    __builtin_amdgcn_s_setprio(0);                                               \
    _Pragma("unroll")                                                            \
    for (int i = 4; i < 8; ++i) aa[i] = *(const bf16x8*)(ab + i * 1024 + rofs);  \
    asm volatile("s_waitcnt lgkmcnt(0)" ::: "memory");                           \
    __builtin_amdgcn_sched_barrier(0);                                           \
    __builtin_amdgcn_s_barrier();                                                \
    if (DOSTAGE) STAGE((T) + 2, d_);                                             \
    __builtin_amdgcn_s_setprio(1);                                               \
    _Pragma("unroll")                                                            \
    for (int i = 4; i < 8; ++i)                                                  \
      _Pragma("unroll")                                                          \
      for (int j = 0; j < 4; ++j)                                                \
        acc[i][j] = mfma16(aa[i], bb[j], acc[i][j]);                             \
    __builtin_amdgcn_s_setprio(0);                                               \
    if (DOEND) {                                                                 \
      asm volatile("s_waitcnt vmcnt(" VMEND ")" ::: "memory");                   \
      __builtin_amdgcn_s_barrier();                                              \
    }                                                                            \
  }

  KTILE(0,  true,  "4", true)
  KTILE(1,  true,  "4", true)
  KTILE(2,  true,  "4", true)
  KTILE(3,  true,  "4", true)
  KTILE(4,  true,  "4", true)
  KTILE(5,  true,  "4", true)
  KTILE(6,  true,  "4", true)
  KTILE(7,  true,  "4", true)
  KTILE(8,  true,  "4", true)
  KTILE(9,  true,  "4", true)
  KTILE(10, true,  "4", true)
  KTILE(11, true,  "4", true)
  KTILE(12, true,  "4", true)
  KTILE(13, true,  "4", true)
  KTILE(14, false, "0", true)
  KTILE(15, false, "0", false)

  // ---- epilogue (r3-proven). C/D: col (l&15) = z-row, row (l>>4)*4+reg = proto.
  f32x4 mu2v[8];
  const int rq = l >> 4;
  #pragma unroll
  for (int i = 0; i < 8; ++i)
    mu2v[i] = *(const f32x4*)&mu2s[wm * 128 + i * 16 + rq * 4];

  __syncthreads();                    // all K-loop LDS reads done; reuse buf area
  float* smf = (float*)smem;          // [256 zrows][36]
  #pragma unroll
  for (int i = 0; i < 8; ++i) {
    const f32x4 m2 = mu2v[i];
    #pragma unroll
    for (int j = 0; j < 4; ++j) {
      const float d0 = fmaf(-2.f, acc[i][j][0], m2[0]);
      const float d1 = fmaf(-2.f, acc[i][j][1], m2[1]);
      const float d2 = fmaf(-2.f, acc[i][j][2], m2[2]);
      const float d3 = fmaf(-2.f, acc[i][j][3], m2[3]);
      float mh = fminf(fminf(d0, d1), fminf(d2, d3));
      float mc = fminf(mh, __shfl_xor(mh, 16));
      if (!(l & 16)) {
        const int zr = wn * 64 + j * 16 + (l & 15);
        const int cl = (wm * 128 + i * 16) / 8 + (l >> 5);
        smf[zr * 36 + cl] = mc;
      }
    }
  }
  __syncthreads();

  const int cb = mt * 32;
  for (int idx = tid; idx < 256 * 8; idx += 512) {
    const int row = idx >> 3, q = idx & 7;
    const int gc = cb + q * 4;
    if (gc < C_CLS) {
      f32x4 v = *(const f32x4*)&smf[row * 36 + q * 4];
      const float zz = z2s[row];
      f32x4 ov = { v[0] + zz, v[1] + zz, v[2] + zz, v[3] + zz };
      const size_t o = (size_t)(nt * 256 + row) * C_CLS + gc;
      *(f32x4*)&mind[o] = ov;
      f32x4 nv = { -ov[0], -ov[1], -ov[2], -ov[3] };
      *(f32x4*)&logits[o] = nv;
    }
  }
}

// ---------- fallback (fp32) in case ws_size is too small ----------
__global__ void fallback_kernel(const float* __restrict__ z, const float* __restrict__ mu,
                                float* __restrict__ logits, float* __restrict__ mind) {
  const int b = blockIdx.x;
  const int w = threadIdx.x >> 6, l = threadIdx.x & 63;
  const int c = blockIdx.y * 4 + w;
  const float* zr = z + (size_t)b * D_DIM;
  float best = 3.4e38f;
  for (int p = 0; p < 8; ++p) {
    const float* m = mu + ((size_t)c * 8 + p) * D_DIM;
    float s = 0.f;
    for (int d = l; d < D_DIM; d += 64) {
      float df = zr[d] - m[d];
      s = fmaf(df, df, s);
    }
    #pragma unroll
    for (int off = 32; off; off >>= 1) s += __shfl_down(s, off);
    s = __shfl(s, 0);
    best = fminf(best, s);
  }
  if (l == 0) {
    logits[(size_t)b * C_CLS + c] = -best;
    mind[(size_t)b * C_CLS + c] = best;
  }
}

extern "C" void kernel_launch(void* const* d_in, const int* in_sizes, int n_in,
                              void* d_out, int out_size, void* d_ws, size_t ws_size,
                              hipStream_t stream) {
  const float* z  = (const float*)d_in[0];
  const float* mu = (const float*)d_in[1];
  float* logits = (float*)d_out;
  float* mind   = logits + (size_t)B_ROWS * C_CLS;

  const size_t zb_bytes  = (size_t)B_ROWS * D_DIM * 2;
  const size_t mub_bytes = (size_t)NPROTO * D_DIM * 2;
  const size_t need = zb_bytes + mub_bytes + (size_t)B_ROWS * 4 + (size_t)NPROTO * 4;

  if (ws_size >= need) {
    char* p = (char*)d_ws;
    __bf16* zb  = (__bf16*)p; p += zb_bytes;
    __bf16* mub = (__bf16*)p; p += mub_bytes;
    float* z2   = (float*)p;  p += (size_t)B_ROWS * 4;
    float* mu2  = (float*)p;
    prep_rows<<<(B_ROWS + NPROTO) / 4, 256, 0, stream>>>(z, mu, zb, mub, z2, mu2);
    proto_gemm<<<MT * NT, 512, 0, stream>>>(zb, mub, z2, mu2, logits, mind);
  } else {
    dim3 g(B_ROWS, C_CLS / 4);
    fallback_kernel<<<g, 256, 0, stream>>>(z, mu, logits, mind);
  }
}

// Round 7
// 158.185 us; speedup vs baseline: 4.2049x; 4.2049x over previous
//
#include <hip/hip_runtime.h>
#include <hip/hip_bf16.h>
#include <stdint.h>
#include <stddef.h>

// z[8192,512] f32, mu[1000,8,512] f32 -> out = concat(logits[8192,1000], min_dist_sq[8192,1000]) f32
#define B_ROWS 8192
#define C_CLS  1000
#define NPROTO 8000
#define D_DIM  512

#define TK 64
#define MT 32                 // proto tiles (A side)
#define NT 32                 // z tiles (B side)

typedef __bf16 bf16x8 __attribute__((ext_vector_type(8)));
typedef float  f32x4  __attribute__((ext_vector_type(4)));

#define AS1 __attribute__((address_space(1)))
#define AS3 __attribute__((address_space(3)))

__device__ __forceinline__ void gload_lds16(const void* g, void* l) {
  __builtin_amdgcn_global_load_lds((const AS1 uint32_t*)g, (AS3 uint32_t*)l, 16, 0, 0);
}

__device__ __forceinline__ f32x4 mfma16(bf16x8 a, bf16x8 b, f32x4 c) {
  return __builtin_amdgcn_mfma_f32_16x16x32_bf16(a, b, c, 0, 0, 0);
}

// LDS map (bytes): buf d: A(mu) at d*65536, B(z) at d*65536+32768; norms above 128K.
// 130 KB -> 1 block/CU (structural: acc AGPRs forbid 2 blocks at this tile anyway).
#define ABUF(d) ((d) * 65536)
#define BBUF(d) ((d) * 65536 + 32768)
#define Z2OFF   131072
#define MU2OFF  132096
#define LDS_BYTES 133120

// ---------- prep: fp32 -> bf16 cast + row sum-of-squares ----------
__global__ void prep_rows(const float* __restrict__ z, const float* __restrict__ mu,
                          __bf16* __restrict__ zb, __bf16* __restrict__ mub,
                          float* __restrict__ z2, float* __restrict__ mu2) {
  const int r = blockIdx.x * 4 + (threadIdx.x >> 6);
  const int l = threadIdx.x & 63;
  const float* src; __bf16* dst; float* sq; int row;
  if (r < B_ROWS) { src = z;  dst = zb;  sq = z2;  row = r; }
  else            { src = mu; dst = mub; sq = mu2; row = r - B_ROWS; }
  const float4* s4 = (const float4*)(src + (size_t)row * D_DIM);
  float4 v0 = s4[l * 2], v1 = s4[l * 2 + 1];
  float ss = v0.x * v0.x + v0.y * v0.y + v0.z * v0.z + v0.w * v0.w
           + v1.x * v1.x + v1.y * v1.y + v1.z * v1.z + v1.w * v1.w;
  bf16x8 o;
  o[0] = (__bf16)v0.x; o[1] = (__bf16)v0.y; o[2] = (__bf16)v0.z; o[3] = (__bf16)v0.w;
  o[4] = (__bf16)v1.x; o[5] = (__bf16)v1.y; o[6] = (__bf16)v1.z; o[7] = (__bf16)v1.w;
  ((bf16x8*)(dst + (size_t)row * D_DIM))[l] = o;
  #pragma unroll
  for (int off = 32; off; off >>= 1) ss += __shfl_down(ss, off);
  if (l == 0) sq[row] = ss;
}

// ---------- fused GEMM(A=mu, B=z) + dist + min-over-P; 4-phase barrier-lockstep ----------
__launch_bounds__(512, 2)
__global__ void proto_gemm(const __bf16* __restrict__ Zb, const __bf16* __restrict__ Mub,
                           const float* __restrict__ Z2, const float* __restrict__ Mu2,
                           float* __restrict__ logits, float* __restrict__ mind) {
  __shared__ __align__(16) unsigned char smem[LDS_BYTES];

  const int tid = threadIdx.x;
  const int l   = tid & 63;
  const int w   = tid >> 6;      // 8 waves: 2 (proto/M) x 4 (zrow/N)
  const int wm  = w >> 2;
  const int wn  = w & 3;

  // T1: XCD chunking (1024 blocks = 8 XCDs x 128)
  const int xcd = blockIdx.x & 7, cc = blockIdx.x >> 3;
  const int mt = (xcd & 1) * 16 + (cc >> 3);   // proto tile
  const int nt = (xcd >> 1) * 8 + (cc & 7);    // z tile

  // norms first (their vmem loads are oldest; retired by the prologue vmcnt(8))
  float* z2s  = (float*)(smem + Z2OFF);
  float* mu2s = (float*)(smem + MU2OFF);
  if (tid < 256) {
    z2s[tid] = Z2[nt * 256 + tid];
  } else {
    const int i = tid - 256;
    const int gp = mt * 256 + i;
    mu2s[i] = Mu2[gp < NPROTO ? gp : NPROTO - 1];
  }

  // staging (both-sides swizzle, r2/r3-proven): linear LDS dest, pre-swizzled global col
  const int sr   = tid >> 3;
  const int scol = ((tid & 7) * 8) ^ ((sr & 7) * 8);
  const __bf16* pA[4]; const __bf16* pB[4];
  #pragma unroll
  for (int q = 0; q < 4; ++q) {
    int rp = mt * 256 + q * 64 + sr;
    if (rp > NPROTO - 1) rp = NPROTO - 1;     // clamp OOB protos (classes write-guarded)
    pA[q] = Mub + (size_t)rp * D_DIM + scol;
    pB[q] = Zb + (size_t)(nt * 256 + q * 64 + sr) * D_DIM + scol;
  }
  const int ldst = tid * 16;

  #define STAGE_A(T, D)                                                      \
    { _Pragma("unroll")                                                      \
      for (int q = 0; q < 4; ++q)                                            \
        gload_lds16(pA[q] + (T) * TK, smem + ABUF(D) + q * 8192 + ldst); }
  #define STAGE_B(T, D)                                                      \
    { _Pragma("unroll")                                                      \
      for (int q = 0; q < 4; ++q)                                            \
        gload_lds16(pB[q] + (T) * TK, smem + BBUF(D) + q * 8192 + ldst); }

  STAGE_A(0, 0); STAGE_B(0, 0);
  STAGE_A(1, 1); STAGE_B(1, 1);

  // swizzled reader offsets (r3-proven): row = base + (l&15); kslice (l>>4)
  const int lx = (l & 7) << 4;
  const int lane_lin = (l & 15) * 128 + (l >> 4) * 16;
  const int ok0 = lane_lin ^ lx;
  const int ok1 = (lane_lin + 64) ^ lx;
  const int abase_w = wm * 16384;   // 128 proto-rows * 128 B
  const int bbase_w = wn * 8192;    // 64 z-rows * 128 B

  f32x4 acc[8][4];
  #pragma unroll
  for (int i = 0; i < 8; ++i)
    #pragma unroll
    for (int j = 0; j < 4; ++j) acc[i][j] = (f32x4){0.f, 0.f, 0.f, 0.f};

  // prologue: norms(1) + stage0(8) + stage1(8) outstanding; vmcnt(8) retires norms+tile0
  asm volatile("s_waitcnt vmcnt(8)" ::: "memory");
  __builtin_amdgcn_s_barrier();

  // 4-phase barrier-lockstep K-tile (m201 pattern): each phase =
  //   {ds_reads for THIS phase | stage} ; s_barrier ; lgkmcnt(0) ; 16 MFMA ; s_barrier
  // Stage-B(T+2) in ph1 (buf.B fully consumed at ph0 -> race-free via ph0 post-barrier);
  // Stage-A(T+2) at tile end (buf.A consumed through ph3). Counted vmcnt(8), never 0 mid-loop.
  #define KPHASE(MFMA_I0)                                                        \
    __builtin_amdgcn_s_barrier();                                                \
    asm volatile("s_waitcnt lgkmcnt(0)" ::: "memory");                           \
    __builtin_amdgcn_sched_barrier(0);                                           \
    __builtin_amdgcn_s_setprio(1);                                               \
    _Pragma("unroll")                                                            \
    for (int j = 0; j < 4; ++j) {                                                \
      acc[MFMA_I0][j]     = mfma16(a0, bb0[j], acc[MFMA_I0][j]);                 \
      acc[MFMA_I0][j]     = mfma16(a1, bb1[j], acc[MFMA_I0][j]);                 \
      acc[MFMA_I0 + 1][j] = mfma16(a2, bb0[j], acc[MFMA_I0 + 1][j]);             \
      acc[MFMA_I0 + 1][j] = mfma16(a3, bb1[j], acc[MFMA_I0 + 1][j]);             \
    }                                                                            \
    __builtin_amdgcn_s_setprio(0);                                               \
    __builtin_amdgcn_s_barrier();

  #define KTILE(T, DOSTAGE, VMEND, DOEND)                                        \
  {                                                                              \
    constexpr int d_ = (T) & 1;                                                  \
    const unsigned char* ab = smem + ABUF(d_) + abase_w;                         \
    const unsigned char* bp = smem + BBUF(d_) + bbase_w;                         \
    bf16x8 bb0[4], bb1[4], a0, a1, a2, a3;                                       \
    /* ph0: B-all + A-q0 */                                                      \
    _Pragma("unroll")                                                            \
    for (int j = 0; j < 4; ++j) {                                                \
      bb0[j] = *(const bf16x8*)(bp + j * 2048 + ok0);                            \
      bb1[j] = *(const bf16x8*)(bp + j * 2048 + ok1);                            \
    }                                                                            \
    a0 = *(const bf16x8*)(ab + 0 * 2048 + ok0);                                  \
    a1 = *(const bf16x8*)(ab + 0 * 2048 + ok1);                                  \
    a2 = *(const bf16x8*)(ab + 1 * 2048 + ok0);                                  \
    a3 = *(const bf16x8*)(ab + 1 * 2048 + ok1);                                  \
    KPHASE(0)                                                                    \
    /* ph1: A-q1 + stage-B(T+2) */                                               \
    a0 = *(const bf16x8*)(ab + 2 * 2048 + ok0);                                  \
    a1 = *(const bf16x8*)(ab + 2 * 2048 + ok1);                                  \
    a2 = *(const bf16x8*)(ab + 3 * 2048 + ok0);                                  \
    a3 = *(const bf16x8*)(ab + 3 * 2048 + ok1);                                  \
    if (DOSTAGE) STAGE_B((T) + 2, d_);                                           \
    KPHASE(2)                                                                    \
    /* ph2: A-q2 */                                                              \
    a0 = *(const bf16x8*)(ab + 4 * 2048 + ok0);                                  \
    a1 = *(const bf16x8*)(ab + 4 * 2048 + ok1);                                  \
    a2 = *(const bf16x8*)(ab + 5 * 2048 + ok0);                                  \
    a3 = *(const bf16x8*)(ab + 5 * 2048 + ok1);                                  \
    KPHASE(4)                                                                    \
    /* ph3: A-q3 */                                                              \
    a0 = *(const bf16x8*)(ab + 6 * 2048 + ok0);                                  \
    a1 = *(const bf16x8*)(ab + 6 * 2048 + ok1);                                  \
    a2 = *(const bf16x8*)(ab + 7 * 2048 + ok0);                                  \
    a3 = *(const bf16x8*)(ab + 7 * 2048 + ok1);                                  \
    KPHASE(6)                                                                    \
    /* tile end: stage-A(T+2) (buf.A fully consumed; ph3 post-barrier passed) */ \
    if (DOSTAGE) STAGE_A((T) + 2, d_);                                           \
    if (DOEND) {                                                                 \
      asm volatile("s_waitcnt vmcnt(" VMEND ")" ::: "memory");                   \
      __builtin_amdgcn_s_barrier();                                              \
    }                                                                            \
  }

  KTILE(0, true,  "8", true)
  KTILE(1, true,  "8", true)
  KTILE(2, true,  "8", true)
  KTILE(3, true,  "8", true)
  KTILE(4, true,  "8", true)
  KTILE(5, true,  "8", true)
  KTILE(6, false, "0", true)
  KTILE(7, false, "0", false)

  // ---- epilogue (r3-proven). C/D: col (l&15) = z-row, row (l>>4)*4+reg = proto.
  f32x4 mu2v[8];
  const int rq = l >> 4;
  #pragma unroll
  for (int i = 0; i < 8; ++i)
    mu2v[i] = *(const f32x4*)&mu2s[wm * 128 + i * 16 + rq * 4];

  __syncthreads();                    // all K-loop LDS reads done; reuse buf area
  float* smf = (float*)smem;          // [256 zrows][36]
  #pragma unroll
  for (int i = 0; i < 8; ++i) {
    const f32x4 m2 = mu2v[i];
    #pragma unroll
    for (int j = 0; j < 4; ++j) {
      const float d0 = fmaf(-2.f, acc[i][j][0], m2[0]);
      const float d1 = fmaf(-2.f, acc[i][j][1], m2[1]);
      const float d2 = fmaf(-2.f, acc[i][j][2], m2[2]);
      const float d3 = fmaf(-2.f, acc[i][j][3], m2[3]);
      float mh = fminf(fminf(d0, d1), fminf(d2, d3));
      float mc = fminf(mh, __shfl_xor(mh, 16));
      if (!(l & 16)) {
        const int zr = wn * 64 + j * 16 + (l & 15);
        const int cl = (wm * 128 + i * 16) / 8 + (l >> 5);
        smf[zr * 36 + cl] = mc;
      }
    }
  }
  __syncthreads();

  const int cb = mt * 32;
  for (int idx = tid; idx < 256 * 8; idx += 512) {
    const int row = idx >> 3, q = idx & 7;
    const int gc = cb + q * 4;
    if (gc < C_CLS) {
      f32x4 v = *(const f32x4*)&smf[row * 36 + q * 4];
      const float zz = z2s[row];
      f32x4 ov = { v[0] + zz, v[1] + zz, v[2] + zz, v[3] + zz };
      const size_t o = (size_t)(nt * 256 + row) * C_CLS + gc;
      *(f32x4*)&mind[o] = ov;
      f32x4 nv = { -ov[0], -ov[1], -ov[2], -ov[3] };
      *(f32x4*)&logits[o] = nv;
    }
  }
}

// ---------- fallback (fp32) in case ws_size is too small ----------
__global__ void fallback_kernel(const float* __restrict__ z, const float* __restrict__ mu,
                                float* __restrict__ logits, float* __restrict__ mind) {
  const int b = blockIdx.x;
  const int w = threadIdx.x >> 6, l = threadIdx.x & 63;
  const int c = blockIdx.y * 4 + w;
  const float* zr = z + (size_t)b * D_DIM;
  float best = 3.4e38f;
  for (int p = 0; p < 8; ++p) {
    const float* m = mu + ((size_t)c * 8 + p) * D_DIM;
    float s = 0.f;
    for (int d = l; d < D_DIM; d += 64) {
      float df = zr[d] - m[d];
      s = fmaf(df, df, s);
    }
    #pragma unroll
    for (int off = 32; off; off >>= 1) s += __shfl_down(s, off);
    s = __shfl(s, 0);
    best = fminf(best, s);
  }
  if (l == 0) {
    logits[(size_t)b * C_CLS + c] = -best;
    mind[(size_t)b * C_CLS + c] = best;
  }
}

extern "C" void kernel_launch(void* const* d_in, const int* in_sizes, int n_in,
                              void* d_out, int out_size, void* d_ws, size_t ws_size,
                              hipStream_t stream) {
  const float* z  = (const float*)d_in[0];
  const float* mu = (const float*)d_in[1];
  float* logits = (float*)d_out;
  float* mind   = logits + (size_t)B_ROWS * C_CLS;

  const size_t zb_bytes  = (size_t)B_ROWS * D_DIM * 2;
  const size_t mub_bytes = (size_t)NPROTO * D_DIM * 2;
  const size_t need = zb_bytes + mub_bytes + (size_t)B_ROWS * 4 + (size_t)NPROTO * 4;

  if (ws_size >= need) {
    char* p = (char*)d_ws;
    __bf16* zb  = (__bf16*)p; p += zb_bytes;
    __bf16* mub = (__bf16*)p; p += mub_bytes;
    float* z2   = (float*)p;  p += (size_t)B_ROWS * 4;
    float* mu2  = (float*)p;
    prep_rows<<<(B_ROWS + NPROTO) / 4, 256, 0, stream>>>(z, mu, zb, mub, z2, mu2);
    proto_gemm<<<MT * NT, 512, 0, stream>>>(zb, mub, z2, mu2, logits, mind);
  } else {
    dim3 g(B_ROWS, C_CLS / 4);
    fallback_kernel<<<g, 256, 0, stream>>>(z, mu, logits, mind);
  }
}